// Round 1
// 279.501 us; speedup vs baseline: 1.0390x; 1.0390x over previous
//
#include <hip/hip_runtime.h>
#include <cstdint>
#include <cstddef>

#define NB    2
#define N1    4096
#define N2    16384
#define CF    64
#define KNN   8
#define SPLIT1 16                 // pass-1 splits
#define NS1   (N1 / SPLIT1)       // 256 candidates per split
#define NQ    (NB * N2)           // 32768 queries

// min/med3 sorted-8 distance network (no index tracking — 8 VALU ops).
#define DNET(d) do { \
    const float m0_ = fminf(d, d0); \
    const float m1_ = __builtin_amdgcn_fmed3f(d, d0, d1); \
    const float m2_ = __builtin_amdgcn_fmed3f(d, d1, d2); \
    const float m3_ = __builtin_amdgcn_fmed3f(d, d2, d3); \
    const float m4_ = __builtin_amdgcn_fmed3f(d, d3, d4); \
    const float m5_ = __builtin_amdgcn_fmed3f(d, d4, d5); \
    const float m6_ = __builtin_amdgcn_fmed3f(d, d5, d6); \
    const float m7_ = __builtin_amdgcn_fmed3f(d, d6, d7); \
    d0=m0_; d1=m1_; d2=m2_; d3=m3_; d4=m4_; d5=m5_; d6=m6_; d7=m7_; \
} while (0)

// exact reference fp32 distance: d = (q2+t2) - (qt+qt), qt=((qx*tx+qy*ty)+qz*tz)
__device__ __forceinline__ float distq(float qx, float qy, float qz, float q2,
                                       float4 p) {
    const float qt = __fadd_rn(
        __fadd_rn(__fmul_rn(qx, p.x), __fmul_rn(qy, p.y)),
        __fmul_rn(qz, p.z));
    return __fsub_rn(__fadd_rn(q2, p.w), __fadd_rn(qt, qt));
}

// ---------------------------------------------------------------------------
// kernel 0: transpose feat1 [B,C,N1] -> feat1T [B,N1,C]; pack xyz1/flow float4
// (aux4.w = t2, exact rounding as the old in-kernel computation); pack queries
// q4 = {x,y,z,q2} — one query per thread across the whole grid (128x256=NQ).
// ---------------------------------------------------------------------------
__global__ __launch_bounds__(256, 2) void k_pack(
    const float* __restrict__ xyz1, const float* __restrict__ xyz2,
    const float* __restrict__ feat1, const float* __restrict__ flow,
    float* __restrict__ feat1T, float4* __restrict__ aux4,
    float4* __restrict__ flow4, float4* __restrict__ q4)
{
    __shared__ float tile[64][65];
    const int b  = blockIdx.y;
    const int n0 = blockIdx.x * 64;
    const int tid = threadIdx.x;
    const int nl = tid & 63, cq = tid >> 6;

#pragma unroll
    for (int r = 0; r < 16; ++r) {
        const int c = r * 4 + cq;
        tile[c][nl] = feat1[((size_t)(b * CF + c)) * N1 + n0 + nl];
    }
    __syncthreads();
#pragma unroll
    for (int r = 0; r < 16; ++r) {
        const int nn = r * 4 + cq;
        feat1T[((size_t)(b * N1 + n0 + nn)) * CF + nl] = tile[nl][nn];
    }
    if (tid < 64) {
        const int n = n0 + tid;
        const float x = xyz1[(b * 3 + 0) * N1 + n];
        const float y = xyz1[(b * 3 + 1) * N1 + n];
        const float z = xyz1[(b * 3 + 2) * N1 + n];
        const float t2 = __fadd_rn(__fadd_rn(__fmul_rn(x, x), __fmul_rn(y, y)),
                                   __fmul_rn(z, z));
        aux4[b * N1 + n] = make_float4(x, y, z, t2);
        const float fx = flow[(b * 3 + 0) * N1 + n];
        const float fy = flow[(b * 3 + 1) * N1 + n];
        const float fz = flow[(b * 3 + 2) * N1 + n];
        flow4[b * N1 + n] = make_float4(fx, fy, fz, 0.f);
    }
    // query pack: grid is (64, 2) x 256 = exactly NQ threads
    {
        const int qid = (blockIdx.y * 64 + blockIdx.x) * 256 + tid;
        const int qb_ = qid >> 14, qn_ = qid & (N2 - 1);
        const float x = xyz2[(qb_ * 3 + 0) * N2 + qn_];
        const float y = xyz2[(qb_ * 3 + 1) * N2 + qn_];
        const float z = xyz2[(qb_ * 3 + 2) * N2 + qn_];
        const float q2 = __fadd_rn(__fadd_rn(__fmul_rn(x, x), __fmul_rn(y, y)),
                                   __fmul_rn(z, z));
        q4[qid] = make_float4(x, y, z, q2);
    }
}

// ---------------------------------------------------------------------------
// kernel 1 (R13-proven math): per-split 8 smallest DISTANCES. QPT=2.
// Now reads packed aux4/q4 (t2/q2 precomputed with identical rounding).
// ---------------------------------------------------------------------------
__global__ __launch_bounds__(256, 4) void k_knn5(
    const float4* __restrict__ aux4, const float4* __restrict__ q4,
    float* __restrict__ partd)
{
    __shared__ float4 pts[NS1];  // {x,y,z,t2} — 4 KiB
    const int sp  = blockIdx.y;
    const int tid = threadIdx.x;
    const int qa  = blockIdx.x * 512 + tid;
    const int qb  = qa + 256;
    const int b   = qa >> 14;    // uniform per block (512 | 16384)

    if (tid < NS1) {
        pts[tid] = aux4[b * N1 + sp * NS1 + tid];
    }
    __syncthreads();

    const float4 A = q4[qa];
    const float4 C = q4[qb];
    const float ax = A.x, ay = A.y, az = A.z, a2 = A.w;
    const float cx = C.x, cy = C.y, cz = C.z, c2 = C.w;

    float Aq0=INFINITY,Aq1=INFINITY,Aq2=INFINITY,Aq3=INFINITY,
          Aq4=INFINITY,Aq5=INFINITY,Aq6=INFINITY,Aq7=INFINITY;
    float Bq0=INFINITY,Bq1=INFINITY,Bq2=INFINITY,Bq3=INFINITY,
          Bq4=INFINITY,Bq5=INFINITY,Bq6=INFINITY,Bq7=INFINITY;

#pragma unroll 4
    for (int j = 0; j < NS1; ++j) {
        const float4 p = pts[j];
        const float dA = distq(ax, ay, az, a2, p);
        const float dB = distq(cx, cy, cz, c2, p);
        {
            float d0=Aq0,d1=Aq1,d2=Aq2,d3=Aq3,d4=Aq4,d5=Aq5,d6=Aq6,d7=Aq7;
            DNET(dA);
            Aq0=d0;Aq1=d1;Aq2=d2;Aq3=d3;Aq4=d4;Aq5=d5;Aq6=d6;Aq7=d7;
        }
        {
            float d0=Bq0,d1=Bq1,d2=Bq2,d3=Bq3,d4=Bq4,d5=Bq5,d6=Bq6,d7=Bq7;
            DNET(dB);
            Bq0=d0;Bq1=d1;Bq2=d2;Bq3=d3;Bq4=d4;Bq5=d5;Bq6=d6;Bq7=d7;
        }
    }

    {
        float* pd = partd + ((size_t)sp * NQ + qa) * KNN;
        pd[0]=Aq0; pd[1]=Aq1; pd[2]=Aq2; pd[3]=Aq3;
        pd[4]=Aq4; pd[5]=Aq5; pd[6]=Aq6; pd[7]=Aq7;
    }
    {
        float* pd = partd + ((size_t)sp * NQ + qb) * KNN;
        pd[0]=Bq0; pd[1]=Bq1; pd[2]=Bq2; pd[3]=Bq3;
        pd[4]=Bq4; pd[5]=Bq5; pd[6]=Bq6; pd[7]=Bq7;
    }
}

// ---------------------------------------------------------------------------
// kernel 2 (R13-proven): merge -> exact global 8th-smallest thr + tneed.
// NEW: also emit per-query active-split mask: bit sp set iff the split's
// minimum distance (partd[sp][q][0]) <= thr — i.e. the split can contain a
// strict hit or a tie. Conservative and exact: every accepted neighbor lives
// in a flagged split.
// ---------------------------------------------------------------------------
__global__ __launch_bounds__(256, 2) void k_thr(
    const float* __restrict__ partd, float* __restrict__ thr,
    int* __restrict__ tneed, int* __restrict__ smask)
{
    const int q = blockIdx.x * 256 + threadIdx.x;
    float d0=INFINITY,d1=INFINITY,d2=INFINITY,d3=INFINITY,
          d4=INFINITY,d5=INFINITY,d6=INFINITY,d7=INFINITY;
    float mn[SPLIT1];

#pragma unroll
    for (int sp = 0; sp < SPLIT1; ++sp) {
        const float* pd = partd + ((size_t)sp * NQ + q) * KNN;
        mn[sp] = pd[0];
#pragma unroll
        for (int r = 0; r < KNN; ++r) {
            const float d = pd[r];
            DNET(d);
        }
    }
    const int s = (d0 < d7) + (d1 < d7) + (d2 < d7) + (d3 < d7) +
                  (d4 < d7) + (d5 < d7) + (d6 < d7);
    int mask = 0;
#pragma unroll
    for (int sp = 0; sp < SPLIT1; ++sp)
        mask |= (mn[sp] <= d7) ? (1 << sp) : 0;

    thr[q]   = d7;
    tneed[q] = 8 - s;
    smask[q] = mask;
}

// ---------------------------------------------------------------------------
// kernel 3 NEW (k_sel5): one wave per query, scan ONLY flagged splits
// (expected ~6.4 of 16), direct coalesced float4 loads of L2-resident aux4
// (t2 precomputed), no LDS staging, no __syncthreads. Splits are
// index-contiguous and scanned in ascending order, so strict hits and
// tie acceptance (ascending index while tc<tn) select the EXACT same 8-set
// as the full scan. Early-exit once 8 accepted.
// ---------------------------------------------------------------------------
__global__ __launch_bounds__(256, 4) void k_sel5(
    const float4* __restrict__ aux4, const float4* __restrict__ q4,
    const float* __restrict__ thr, const int* __restrict__ tneed,
    const int* __restrict__ smask, int* __restrict__ knn_idx)
{
    const int tid  = threadIdx.x;
    const int wave = tid >> 6, lane = tid & 63;
    const int q    = blockIdx.x * 4 + wave;
    const int b    = q >> 14;

    const float4 qv   = q4[q];
    const float  thrq = thr[q];
    const int    tn   = tneed[q];
    int mask = smask[q];

    int pos = 0, tc = 0;
    int* ko = knn_idx + (size_t)q * KNN;
    const float4* pts = aux4 + b * N1;

    while (mask) {
        const int sp = __builtin_ctz(mask); mask &= mask - 1;
        const int jb = sp * NS1;
#pragma unroll
        for (int t = 0; t < 4; ++t) {
            const float4 p = pts[jb + t * 64 + lane];
            const float d = distq(qv.x, qv.y, qv.z, qv.w, p);
            unsigned long long s = __ballot(d <  thrq);
            unsigned long long e = __ballot(d == thrq);
            const int jbase = jb + t * 64;
            while (s) {
                const int bit = __builtin_ctzll(s); s &= s - 1;
                if (lane == 0 && pos < 8) ko[pos] = jbase + bit;
                ++pos;
            }
            while (e && tc < tn) {
                const int bit = __builtin_ctzll(e); e &= e - 1;
                if (lane == 0 && pos < 8) ko[pos] = jbase + bit;
                ++pos; ++tc;
            }
        }
        if (pos >= 8) break;
    }
}

// ---------------------------------------------------------------------------
// kernel 4: MLP v5 — EXACT R13/R15 version (115-116 us proven best).
// ---------------------------------------------------------------------------
#define R4(WV, C4, BK) { \
    const float4 i0_ = *(const float4*)(inw + ((BK)+0)*68 + (C4)*4); \
    const float4 i1_ = *(const float4*)(inw + ((BK)+1)*68 + (C4)*4); \
    const float4 i2_ = *(const float4*)(inw + ((BK)+2)*68 + (C4)*4); \
    const float4 i3_ = *(const float4*)(inw + ((BK)+3)*68 + (C4)*4); \
    ha = fmaf((WV).x, i0_.x, ha); ha = fmaf((WV).y, i0_.y, ha); \
    ha = fmaf((WV).z, i0_.z, ha); ha = fmaf((WV).w, i0_.w, ha); \
    hb = fmaf((WV).x, i1_.x, hb); hb = fmaf((WV).y, i1_.y, hb); \
    hb = fmaf((WV).z, i1_.z, hb); hb = fmaf((WV).w, i1_.w, hb); \
    hc = fmaf((WV).x, i2_.x, hc); hc = fmaf((WV).y, i2_.y, hc); \
    hc = fmaf((WV).z, i2_.z, hc); hc = fmaf((WV).w, i2_.w, hc); \
    hd = fmaf((WV).x, i3_.x, hd); hd = fmaf((WV).y, i3_.y, hd); \
    hd = fmaf((WV).z, i3_.z, hd); hd = fmaf((WV).w, i3_.w, hd); \
}

#define DPP1(v, CTRL, RM) \
    v += __int_as_float(__builtin_amdgcn_update_dpp( \
        0, __float_as_int(v), CTRL, RM, 0xF, false))

#define DPPALL(CTRL, RM) do { \
    DPP1(pa0,CTRL,RM); DPP1(pb0,CTRL,RM); DPP1(pc0,CTRL,RM); DPP1(pd0,CTRL,RM); \
    DPP1(pa1,CTRL,RM); DPP1(pb1,CTRL,RM); DPP1(pc1,CTRL,RM); DPP1(pd1,CTRL,RM); \
    DPP1(pa2,CTRL,RM); DPP1(pb2,CTRL,RM); DPP1(pc2,CTRL,RM); DPP1(pd2,CTRL,RM); \
} while (0)

#define RDL(v) __int_as_float(__builtin_amdgcn_readlane(__float_as_int(v), 63))

#define L1L2_QUAD(BK, SA0,SA1,SA2,SA3, SB0,SB1,SB2,SB3, SC0,SC1,SC2,SC3) do { \
    float ha = b1v, hb = b1v, hc = b1v, hd = b1v; \
    R4(w0, 0, BK)  R4(w1, 1, BK)  R4(w2, 2, BK)  R4(w3, 3, BK) \
    R4(w4, 4, BK)  R4(w5, 5, BK)  R4(w6, 6, BK)  R4(w7, 7, BK) \
    R4(w8, 8, BK)  R4(w9, 9, BK)  R4(w10,10, BK) R4(w11,11, BK) \
    R4(w12,12, BK) R4(w13,13, BK) R4(w14,14, BK) R4(w15,15, BK) \
    R4(w16,16, BK) \
    ha = ha >= 0.f ? ha : 0.1f * ha; \
    hb = hb >= 0.f ? hb : 0.1f * hb; \
    hc = hc >= 0.f ? hc : 0.1f * hc; \
    hd = hd >= 0.f ? hd : 0.1f * hd; \
    float pa0 = w2a*ha, pb0 = w2a*hb, pc0 = w2a*hc, pd0 = w2a*hd; \
    float pa1 = w2b*ha, pb1 = w2b*hb, pc1 = w2b*hc, pd1 = w2b*hd; \
    float pa2 = w2c*ha, pb2 = w2c*hb, pc2 = w2c*hc, pd2 = w2c*hd; \
    DPPALL(0x111, 0xF); DPPALL(0x112, 0xF); DPPALL(0x114, 0xF); \
    DPPALL(0x118, 0xF); DPPALL(0x142, 0xA); DPPALL(0x143, 0xC); \
    SA0 = RDL(pa0) + b20; SA1 = RDL(pb0) + b20; \
    SA2 = RDL(pc0) + b20; SA3 = RDL(pd0) + b20; \
    SB0 = RDL(pa1) + b21; SB1 = RDL(pb1) + b21; \
    SB2 = RDL(pc1) + b21; SB3 = RDL(pd1) + b21; \
    SC0 = RDL(pa2) + b22; SC1 = RDL(pb2) + b22; \
    SC2 = RDL(pc2) + b22; SC3 = RDL(pd2) + b22; \
} while (0)

#define SMAX8(sa, sb, sc, sd, se, sf, sg, sh, CH, res) do { \
    const float m_ = fmaxf(fmaxf(fmaxf(sa, sb), fmaxf(sc, sd)), \
                           fmaxf(fmaxf(se, sf), fmaxf(sg, sh))); \
    const float e0_ = __expf(sa - m_), e1_ = __expf(sb - m_); \
    const float e2_ = __expf(sc - m_), e3_ = __expf(sd - m_); \
    const float e4_ = __expf(se - m_), e5_ = __expf(sf - m_); \
    const float e6_ = __expf(sg - m_), e7_ = __expf(sh - m_); \
    const float S_ = ((e0_ + e1_) + (e2_ + e3_)) + ((e4_ + e5_) + (e6_ + e7_)); \
    float acc_ = e0_ * flf[0 * 4 + CH]; \
    acc_ = fmaf(e1_, flf[1 * 4 + CH], acc_); acc_ = fmaf(e2_, flf[2 * 4 + CH], acc_); \
    acc_ = fmaf(e3_, flf[3 * 4 + CH], acc_); acc_ = fmaf(e4_, flf[4 * 4 + CH], acc_); \
    acc_ = fmaf(e5_, flf[5 * 4 + CH], acc_); acc_ = fmaf(e6_, flf[6 * 4 + CH], acc_); \
    acc_ = fmaf(e7_, flf[7 * 4 + CH], acc_); \
    res = acc_ / S_; \
} while (0)

#define MLP_STEP(IT) do { \
    const int n_ = n0 + (IT); \
    __builtin_amdgcn_wave_barrier(); \
    float4* drow = (float4*)(inw + k * 68); \
    drow[p * 2] = g0; drow[p * 2 + 1] = g1; \
    if (p == 0) { \
        inw[k * 68 + 64] = axv.x - qx; inw[k * 68 + 65] = axv.y - qy; \
        inw[k * 68 + 66] = axv.z - qz; inw[k * 68 + 67] = 0.f; \
    } \
    if (p == 1) flbuf[wave][k] = flv; \
    __builtin_amdgcn_wave_barrier(); \
    if ((IT) < 7) { \
        const int idn_ = idnext; \
        const float4* fr_ = (const float4*)(feat1T + (size_t)(base + idn_) * CF); \
        g0 = fr_[p * 2]; g1 = fr_[p * 2 + 1]; \
        axv = aux4[base + idn_]; flv = flow4[base + idn_]; \
        qx = xyz2[(b * 3 + 0) * N2 + n_ + 1]; \
        qy = xyz2[(b * 3 + 1) * N2 + n_ + 1]; \
        qz = xyz2[(b * 3 + 2) * N2 + n_ + 1]; \
        if ((IT) < 6) idnext = knn_idx[(size_t)(q0 + (IT) + 2) * KNN + k]; \
    } \
    float s00, s01, s02, s03, s04, s05, s06, s07; \
    float s10, s11, s12, s13, s14, s15, s16, s17; \
    float s20, s21, s22, s23, s24, s25, s26, s27; \
    L1L2_QUAD(0, s00,s01,s02,s03, s10,s11,s12,s13, s20,s21,s22,s23); \
    L1L2_QUAD(4, s04,s05,s06,s07, s14,s15,s16,s17, s24,s25,s26,s27); \
    float res0, res1, res2; \
    SMAX8(s00, s01, s02, s03, s04, s05, s06, s07, 0, res0); \
    SMAX8(s10, s11, s12, s13, s14, s15, s16, s17, 1, res1); \
    SMAX8(s20, s21, s22, s23, s24, s25, s26, s27, 2, res2); \
    const float resv = lane == 0 ? res0 : (lane == 1 ? res1 : res2); \
    if (lane < 3) out[((size_t)(b * 3 + lane)) * N2 + n_] = resv; \
} while (0)

__global__ __launch_bounds__(256, 2) void k_mlp5(
    const float* __restrict__ feat1T, const float4* __restrict__ aux4,
    const float4* __restrict__ flow4, const int* __restrict__ knn_idx,
    const float* __restrict__ xyz2,
    const float* __restrict__ W1, const float* __restrict__ b1,
    const float* __restrict__ W2, const float* __restrict__ b2,
    float* __restrict__ out)
{
    __shared__ __align__(16) float w1s[64 * 68];
    __shared__ __align__(16) float inbuf[4][8][68];
    __shared__ __align__(16) float4 flbuf[4][8];

    const int tid  = threadIdx.x;
    const int wave = tid >> 6, lane = tid & 63;

    for (int t = tid; t < 64 * 67; t += 256) {
        const int o = t / 67, c = t - o * 67;
        w1s[o * 68 + c] = W1[t];
    }
    if (tid < 64) w1s[tid * 68 + 67] = 0.f;

    const float b1v = b1[lane];
    const float w2a = W2[lane], w2b = W2[64 + lane], w2c = W2[128 + lane];
    const float b20 = b2[0], b21 = b2[1], b22 = b2[2];
    __syncthreads();

    const float4* wr = (const float4*)&w1s[lane * 68];
    const float4 w0 = wr[0],  w1 = wr[1],  w2 = wr[2],  w3 = wr[3];
    const float4 w4 = wr[4],  w5 = wr[5],  w6 = wr[6],  w7 = wr[7];
    const float4 w8 = wr[8],  w9 = wr[9],  w10 = wr[10], w11 = wr[11];
    const float4 w12 = wr[12], w13 = wr[13], w14 = wr[14], w15 = wr[15];
    const float4 w16 = wr[16];

    const int k = lane >> 3, p = lane & 7;
    float* inw = &inbuf[wave][0][0];
    const float* flf = (const float*)&flbuf[wave][0];

    const int q0   = blockIdx.x * 32 + wave * 8;
    const int b    = q0 >> 14;
    const int base = b * N1;
    const int n0   = q0 & (N2 - 1);

    const int id0v = knn_idx[(size_t)q0 * KNN + k];
    int idnext     = knn_idx[(size_t)(q0 + 1) * KNN + k];

    const float4* fr0 = (const float4*)(feat1T + (size_t)(base + id0v) * CF);
    float4 g0 = fr0[p * 2], g1 = fr0[p * 2 + 1];
    float4 axv = aux4[base + id0v];
    float4 flv = flow4[base + id0v];
    float qx = xyz2[(b * 3 + 0) * N2 + n0];
    float qy = xyz2[(b * 3 + 1) * N2 + n0];
    float qz = xyz2[(b * 3 + 2) * N2 + n0];

    MLP_STEP(0);
    MLP_STEP(1);
    MLP_STEP(2);
    MLP_STEP(3);
    MLP_STEP(4);
    MLP_STEP(5);
    MLP_STEP(6);
    MLP_STEP(7);
}

// ---------------------------------------------------------------------------
extern "C" void kernel_launch(void* const* d_in, const int* in_sizes, int n_in,
                              void* d_out, int out_size, void* d_ws, size_t ws_size,
                              hipStream_t stream)
{
    const float* xyz1  = (const float*)d_in[0];
    const float* xyz2  = (const float*)d_in[1];
    const float* feat1 = (const float*)d_in[2];
    const float* flow  = (const float*)d_in[3];
    const float* W1    = (const float*)d_in[4];
    const float* b1    = (const float*)d_in[5];
    const float* W2    = (const float*)d_in[6];
    const float* b2    = (const float*)d_in[7];
    float* out = (float*)d_out;

    // ws layout: feat1T 2M @0 | aux4 .5M @2M | flow4 .5M @2.5M |
    //            knn_idx 1M @3M | partd 16M @4M | thr .5M @20M |
    //            tneed .5M @20.5M | smask .5M @21M | q4 .5M @21.5M
    //            (22 MiB total; 35.25 proven in R9)
    char* ws = (char*)d_ws;
    float*  feat1T  = (float*)(ws);
    float4* aux4    = (float4*)(ws + (size_t)(2u << 20));
    float4* flow4   = (float4*)(ws + (size_t)(2u << 20) + (512u << 10));
    int*    knn_idx = (int*)  (ws + (size_t)(3u << 20));
    float*  partd   = (float*)(ws + (size_t)(4u << 20));
    float*  thr     = (float*)(ws + (size_t)(20u << 20));
    int*    tneed   = (int*)  (ws + (size_t)(20u << 20) + (512u << 10));
    int*    smask   = (int*)  (ws + (size_t)(21u << 20));
    float4* q4      = (float4*)(ws + (size_t)(21u << 20) + (512u << 10));

    hipLaunchKernelGGL(k_pack, dim3(N1 / 64, NB), dim3(256), 0, stream,
                       xyz1, xyz2, feat1, flow, feat1T, aux4, flow4, q4);
    hipLaunchKernelGGL(k_knn5, dim3(NQ / 512, SPLIT1), dim3(256), 0, stream,
                       aux4, q4, partd);
    hipLaunchKernelGGL(k_thr, dim3(NQ / 256), dim3(256), 0, stream,
                       partd, thr, tneed, smask);
    hipLaunchKernelGGL(k_sel5, dim3(NQ / 4), dim3(256), 0, stream,
                       aux4, q4, thr, tneed, smask, knn_idx);
    hipLaunchKernelGGL(k_mlp5, dim3(NQ / 32), dim3(256), 0, stream,
                       feat1T, aux4, flow4, knn_idx, xyz2, W1, b1, W2, b2, out);
}

// Round 2
// 270.041 us; speedup vs baseline: 1.0754x; 1.0350x over previous
//
#include <hip/hip_runtime.h>
#include <cstdint>
#include <cstddef>

#define NB    2
#define N1    4096
#define N2    16384
#define CF    64
#define KNN   8
#define SPLIT1 16                 // pass-1 splits
#define NS1   (N1 / SPLIT1)       // 256 candidates per split
#define NQ    (NB * N2)           // 32768 queries

// min/med3 sorted-8 distance network (no index tracking — 8 VALU ops).
#define DNET(d) do { \
    const float m0_ = fminf(d, d0); \
    const float m1_ = __builtin_amdgcn_fmed3f(d, d0, d1); \
    const float m2_ = __builtin_amdgcn_fmed3f(d, d1, d2); \
    const float m3_ = __builtin_amdgcn_fmed3f(d, d2, d3); \
    const float m4_ = __builtin_amdgcn_fmed3f(d, d3, d4); \
    const float m5_ = __builtin_amdgcn_fmed3f(d, d4, d5); \
    const float m6_ = __builtin_amdgcn_fmed3f(d, d5, d6); \
    const float m7_ = __builtin_amdgcn_fmed3f(d, d6, d7); \
    d0=m0_; d1=m1_; d2=m2_; d3=m3_; d4=m4_; d5=m5_; d6=m6_; d7=m7_; \
} while (0)

// exact reference fp32 distance: d = (q2+t2) - (qt+qt), qt=((qx*tx+qy*ty)+qz*tz)
__device__ __forceinline__ float distq(float qx, float qy, float qz, float q2,
                                       float4 p) {
    const float qt = __fadd_rn(
        __fadd_rn(__fmul_rn(qx, p.x), __fmul_rn(qy, p.y)),
        __fmul_rn(qz, p.z));
    return __fsub_rn(__fadd_rn(q2, p.w), __fadd_rn(qt, qt));
}

// ---------------------------------------------------------------------------
// kernel 0: transpose feat1 [B,C,N1] -> feat1T [B,N1,C]; pack xyz1/flow float4
// (aux4.w = t2); pack queries q4 = {x,y,z,q2}.
// ---------------------------------------------------------------------------
__global__ __launch_bounds__(256, 2) void k_pack(
    const float* __restrict__ xyz1, const float* __restrict__ xyz2,
    const float* __restrict__ feat1, const float* __restrict__ flow,
    float* __restrict__ feat1T, float4* __restrict__ aux4,
    float4* __restrict__ flow4, float4* __restrict__ q4)
{
    __shared__ float tile[64][65];
    const int b  = blockIdx.y;
    const int n0 = blockIdx.x * 64;
    const int tid = threadIdx.x;
    const int nl = tid & 63, cq = tid >> 6;

#pragma unroll
    for (int r = 0; r < 16; ++r) {
        const int c = r * 4 + cq;
        tile[c][nl] = feat1[((size_t)(b * CF + c)) * N1 + n0 + nl];
    }
    __syncthreads();
#pragma unroll
    for (int r = 0; r < 16; ++r) {
        const int nn = r * 4 + cq;
        feat1T[((size_t)(b * N1 + n0 + nn)) * CF + nl] = tile[nl][nn];
    }
    if (tid < 64) {
        const int n = n0 + tid;
        const float x = xyz1[(b * 3 + 0) * N1 + n];
        const float y = xyz1[(b * 3 + 1) * N1 + n];
        const float z = xyz1[(b * 3 + 2) * N1 + n];
        const float t2 = __fadd_rn(__fadd_rn(__fmul_rn(x, x), __fmul_rn(y, y)),
                                   __fmul_rn(z, z));
        aux4[b * N1 + n] = make_float4(x, y, z, t2);
        const float fx = flow[(b * 3 + 0) * N1 + n];
        const float fy = flow[(b * 3 + 1) * N1 + n];
        const float fz = flow[(b * 3 + 2) * N1 + n];
        flow4[b * N1 + n] = make_float4(fx, fy, fz, 0.f);
    }
    {
        const int qid = (blockIdx.y * 64 + blockIdx.x) * 256 + tid;
        const int qb_ = qid >> 14, qn_ = qid & (N2 - 1);
        const float x = xyz2[(qb_ * 3 + 0) * N2 + qn_];
        const float y = xyz2[(qb_ * 3 + 1) * N2 + qn_];
        const float z = xyz2[(qb_ * 3 + 2) * N2 + qn_];
        const float q2 = __fadd_rn(__fadd_rn(__fmul_rn(x, x), __fmul_rn(y, y)),
                                   __fmul_rn(z, z));
        q4[qid] = make_float4(x, y, z, q2);
    }
}

// ---------------------------------------------------------------------------
// kernel 1: per-split 8 smallest DISTANCES. QPT=2. partd stores now float4x2
// (was 8 stride-8 scalar dwords — 4x fewer store instrs / partial lines).
// ---------------------------------------------------------------------------
__global__ __launch_bounds__(256, 4) void k_knn5(
    const float4* __restrict__ aux4, const float4* __restrict__ q4,
    float* __restrict__ partd)
{
    __shared__ float4 pts[NS1];  // {x,y,z,t2} — 4 KiB
    const int sp  = blockIdx.y;
    const int tid = threadIdx.x;
    const int qa  = blockIdx.x * 512 + tid;
    const int qb  = qa + 256;
    const int b   = qa >> 14;    // uniform per block (512 | 16384)

    if (tid < NS1) {
        pts[tid] = aux4[b * N1 + sp * NS1 + tid];
    }
    __syncthreads();

    const float4 A = q4[qa];
    const float4 C = q4[qb];
    const float ax = A.x, ay = A.y, az = A.z, a2 = A.w;
    const float cx = C.x, cy = C.y, cz = C.z, c2 = C.w;

    float Aq0=INFINITY,Aq1=INFINITY,Aq2=INFINITY,Aq3=INFINITY,
          Aq4=INFINITY,Aq5=INFINITY,Aq6=INFINITY,Aq7=INFINITY;
    float Bq0=INFINITY,Bq1=INFINITY,Bq2=INFINITY,Bq3=INFINITY,
          Bq4=INFINITY,Bq5=INFINITY,Bq6=INFINITY,Bq7=INFINITY;

#pragma unroll 4
    for (int j = 0; j < NS1; ++j) {
        const float4 p = pts[j];
        const float dA = distq(ax, ay, az, a2, p);
        const float dB = distq(cx, cy, cz, c2, p);
        {
            float d0=Aq0,d1=Aq1,d2=Aq2,d3=Aq3,d4=Aq4,d5=Aq5,d6=Aq6,d7=Aq7;
            DNET(dA);
            Aq0=d0;Aq1=d1;Aq2=d2;Aq3=d3;Aq4=d4;Aq5=d5;Aq6=d6;Aq7=d7;
        }
        {
            float d0=Bq0,d1=Bq1,d2=Bq2,d3=Bq3,d4=Bq4,d5=Bq5,d6=Bq6,d7=Bq7;
            DNET(dB);
            Bq0=d0;Bq1=d1;Bq2=d2;Bq3=d3;Bq4=d4;Bq5=d5;Bq6=d6;Bq7=d7;
        }
    }

    {
        float4* pd4 = (float4*)(partd + ((size_t)sp * NQ + qa) * KNN);
        pd4[0] = make_float4(Aq0, Aq1, Aq2, Aq3);
        pd4[1] = make_float4(Aq4, Aq5, Aq6, Aq7);
    }
    {
        float4* pd4 = (float4*)(partd + ((size_t)sp * NQ + qb) * KNN);
        pd4[0] = make_float4(Bq0, Bq1, Bq2, Bq3);
        pd4[1] = make_float4(Bq4, Bq5, Bq6, Bq7);
    }
}

// ---------------------------------------------------------------------------
// kernel 2: merge -> exact global 8th-smallest thr + tneed + active-split mask
// (bit sp set iff split-min <= thr). partd loads now float4x2.
// ---------------------------------------------------------------------------
__global__ __launch_bounds__(256, 2) void k_thr(
    const float* __restrict__ partd, float* __restrict__ thr,
    int* __restrict__ tneed, int* __restrict__ smask)
{
    const int q = blockIdx.x * 256 + threadIdx.x;
    float d0=INFINITY,d1=INFINITY,d2=INFINITY,d3=INFINITY,
          d4=INFINITY,d5=INFINITY,d6=INFINITY,d7=INFINITY;
    float mn[SPLIT1];

#pragma unroll
    for (int sp = 0; sp < SPLIT1; ++sp) {
        const float4* pd4 = (const float4*)(partd + ((size_t)sp * NQ + q) * KNN);
        const float4 lo = pd4[0], hi = pd4[1];
        mn[sp] = lo.x;
        { const float d = lo.x; DNET(d); }
        { const float d = lo.y; DNET(d); }
        { const float d = lo.z; DNET(d); }
        { const float d = lo.w; DNET(d); }
        { const float d = hi.x; DNET(d); }
        { const float d = hi.y; DNET(d); }
        { const float d = hi.z; DNET(d); }
        { const float d = hi.w; DNET(d); }
    }
    const int s = (d0 < d7) + (d1 < d7) + (d2 < d7) + (d3 < d7) +
                  (d4 < d7) + (d5 < d7) + (d6 < d7);
    int mask = 0;
#pragma unroll
    for (int sp = 0; sp < SPLIT1; ++sp)
        mask |= (mn[sp] <= d7) ? (1 << sp) : 0;

    thr[q]   = d7;
    tneed[q] = 8 - s;
    smask[q] = mask;
}

// ---------------------------------------------------------------------------
// kernel 3 (k_sel5): one wave per query, scan ONLY flagged splits in ascending
// order — exact same 8-set as full scan. Early-exit once 8 accepted.
// ---------------------------------------------------------------------------
__global__ __launch_bounds__(256, 4) void k_sel5(
    const float4* __restrict__ aux4, const float4* __restrict__ q4,
    const float* __restrict__ thr, const int* __restrict__ tneed,
    const int* __restrict__ smask, int* __restrict__ knn_idx)
{
    const int tid  = threadIdx.x;
    const int wave = tid >> 6, lane = tid & 63;
    const int q    = blockIdx.x * 4 + wave;
    const int b    = q >> 14;

    const float4 qv   = q4[q];
    const float  thrq = thr[q];
    const int    tn   = tneed[q];
    int mask = smask[q];

    int pos = 0, tc = 0;
    int* ko = knn_idx + (size_t)q * KNN;
    const float4* pts = aux4 + b * N1;

    while (mask) {
        const int sp = __builtin_ctz(mask); mask &= mask - 1;
        const int jb = sp * NS1;
#pragma unroll
        for (int t = 0; t < 4; ++t) {
            const float4 p = pts[jb + t * 64 + lane];
            const float d = distq(qv.x, qv.y, qv.z, qv.w, p);
            unsigned long long s = __ballot(d <  thrq);
            unsigned long long e = __ballot(d == thrq);
            const int jbase = jb + t * 64;
            while (s) {
                const int bit = __builtin_ctzll(s); s &= s - 1;
                if (lane == 0 && pos < 8) ko[pos] = jbase + bit;
                ++pos;
            }
            while (e && tc < tn) {
                const int bit = __builtin_ctzll(e); e &= e - 1;
                if (lane == 0 && pos < 8) ko[pos] = jbase + bit;
                ++pos; ++tc;
            }
        }
        if (pos >= 8) break;
    }
}

// ---------------------------------------------------------------------------
// kernel 4: MLP v6 — R13/R15 math, but the 64-lane W2-reduction now uses
// FUSED v_add_f32_dpp (1 instr/stage instead of mov0+mov_dpp+add = 3), and
// softmax divide -> v_rcp_f32 * mul. Data movement is ctrl-identical to the
// proven update_dpp version (masked-off / invalid-source lanes contribute 0
// either way). VALU->DPP-read hazard (2 wait states) is guaranteed by
// construction: each stage is ONE asm block of 12 interleaved independent
// chains (dependent DPPs are 11 instrs apart) with s_nop 1 guarding block
// entry (after the w2*h muls) and exit (before v_readlane).
// ---------------------------------------------------------------------------
#define R4(WV, C4, BK) { \
    const float4 i0_ = *(const float4*)(inw + ((BK)+0)*68 + (C4)*4); \
    const float4 i1_ = *(const float4*)(inw + ((BK)+1)*68 + (C4)*4); \
    const float4 i2_ = *(const float4*)(inw + ((BK)+2)*68 + (C4)*4); \
    const float4 i3_ = *(const float4*)(inw + ((BK)+3)*68 + (C4)*4); \
    ha = fmaf((WV).x, i0_.x, ha); ha = fmaf((WV).y, i0_.y, ha); \
    ha = fmaf((WV).z, i0_.z, ha); ha = fmaf((WV).w, i0_.w, ha); \
    hb = fmaf((WV).x, i1_.x, hb); hb = fmaf((WV).y, i1_.y, hb); \
    hb = fmaf((WV).z, i1_.z, hb); hb = fmaf((WV).w, i1_.w, hb); \
    hc = fmaf((WV).x, i2_.x, hc); hc = fmaf((WV).y, i2_.y, hc); \
    hc = fmaf((WV).z, i2_.z, hc); hc = fmaf((WV).w, i2_.w, hc); \
    hd = fmaf((WV).x, i3_.x, hd); hd = fmaf((WV).y, i3_.y, hd); \
    hd = fmaf((WV).z, i3_.z, hd); hd = fmaf((WV).w, i3_.w, hd); \
}

// one reduction stage: 12 fused dpp-adds, interleaved chains (hazard-safe).
#define DPPS12(PRE, MODS, POST) \
    asm(PRE \
        "v_add_f32_dpp %0, %0, %0 "   MODS "\n\t" \
        "v_add_f32_dpp %1, %1, %1 "   MODS "\n\t" \
        "v_add_f32_dpp %2, %2, %2 "   MODS "\n\t" \
        "v_add_f32_dpp %3, %3, %3 "   MODS "\n\t" \
        "v_add_f32_dpp %4, %4, %4 "   MODS "\n\t" \
        "v_add_f32_dpp %5, %5, %5 "   MODS "\n\t" \
        "v_add_f32_dpp %6, %6, %6 "   MODS "\n\t" \
        "v_add_f32_dpp %7, %7, %7 "   MODS "\n\t" \
        "v_add_f32_dpp %8, %8, %8 "   MODS "\n\t" \
        "v_add_f32_dpp %9, %9, %9 "   MODS "\n\t" \
        "v_add_f32_dpp %10, %10, %10 " MODS "\n\t" \
        "v_add_f32_dpp %11, %11, %11 " MODS POST \
        : "+v"(pa0), "+v"(pb0), "+v"(pc0), "+v"(pd0), \
          "+v"(pa1), "+v"(pb1), "+v"(pc1), "+v"(pd1), \
          "+v"(pa2), "+v"(pb2), "+v"(pc2), "+v"(pd2))

#define RDL(v) __int_as_float(__builtin_amdgcn_readlane(__float_as_int(v), 63))

#define L1L2_QUAD(BK, SA0,SA1,SA2,SA3, SB0,SB1,SB2,SB3, SC0,SC1,SC2,SC3) do { \
    float ha = b1v, hb = b1v, hc = b1v, hd = b1v; \
    R4(w0, 0, BK)  R4(w1, 1, BK)  R4(w2, 2, BK)  R4(w3, 3, BK) \
    R4(w4, 4, BK)  R4(w5, 5, BK)  R4(w6, 6, BK)  R4(w7, 7, BK) \
    R4(w8, 8, BK)  R4(w9, 9, BK)  R4(w10,10, BK) R4(w11,11, BK) \
    R4(w12,12, BK) R4(w13,13, BK) R4(w14,14, BK) R4(w15,15, BK) \
    R4(w16,16, BK) \
    ha = ha >= 0.f ? ha : 0.1f * ha; \
    hb = hb >= 0.f ? hb : 0.1f * hb; \
    hc = hc >= 0.f ? hc : 0.1f * hc; \
    hd = hd >= 0.f ? hd : 0.1f * hd; \
    float pa0 = w2a*ha, pb0 = w2a*hb, pc0 = w2a*hc, pd0 = w2a*hd; \
    float pa1 = w2b*ha, pb1 = w2b*hb, pc1 = w2b*hc, pd1 = w2b*hd; \
    float pa2 = w2c*ha, pb2 = w2c*hb, pc2 = w2c*hc, pd2 = w2c*hd; \
    DPPS12("s_nop 1\n\t", "row_shr:1 row_mask:0xf bank_mask:0xf", ""); \
    DPPS12("", "row_shr:2 row_mask:0xf bank_mask:0xf", ""); \
    DPPS12("", "row_shr:4 row_mask:0xf bank_mask:0xf", ""); \
    DPPS12("", "row_shr:8 row_mask:0xf bank_mask:0xf", ""); \
    DPPS12("", "row_bcast:15 row_mask:0xa bank_mask:0xf", ""); \
    DPPS12("", "row_bcast:31 row_mask:0xc bank_mask:0xf", "\n\ts_nop 1"); \
    SA0 = RDL(pa0) + b20; SA1 = RDL(pb0) + b20; \
    SA2 = RDL(pc0) + b20; SA3 = RDL(pd0) + b20; \
    SB0 = RDL(pa1) + b21; SB1 = RDL(pb1) + b21; \
    SB2 = RDL(pc1) + b21; SB3 = RDL(pd1) + b21; \
    SC0 = RDL(pa2) + b22; SC1 = RDL(pb2) + b22; \
    SC2 = RDL(pc2) + b22; SC3 = RDL(pd2) + b22; \
} while (0)

#define SMAX8(sa, sb, sc, sd, se, sf, sg, sh, CH, res) do { \
    const float m_ = fmaxf(fmaxf(fmaxf(sa, sb), fmaxf(sc, sd)), \
                           fmaxf(fmaxf(se, sf), fmaxf(sg, sh))); \
    const float e0_ = __expf(sa - m_), e1_ = __expf(sb - m_); \
    const float e2_ = __expf(sc - m_), e3_ = __expf(sd - m_); \
    const float e4_ = __expf(se - m_), e5_ = __expf(sf - m_); \
    const float e6_ = __expf(sg - m_), e7_ = __expf(sh - m_); \
    const float S_ = ((e0_ + e1_) + (e2_ + e3_)) + ((e4_ + e5_) + (e6_ + e7_)); \
    float acc_ = e0_ * flf[0 * 4 + CH]; \
    acc_ = fmaf(e1_, flf[1 * 4 + CH], acc_); acc_ = fmaf(e2_, flf[2 * 4 + CH], acc_); \
    acc_ = fmaf(e3_, flf[3 * 4 + CH], acc_); acc_ = fmaf(e4_, flf[4 * 4 + CH], acc_); \
    acc_ = fmaf(e5_, flf[5 * 4 + CH], acc_); acc_ = fmaf(e6_, flf[6 * 4 + CH], acc_); \
    acc_ = fmaf(e7_, flf[7 * 4 + CH], acc_); \
    res = acc_ * __builtin_amdgcn_rcpf(S_); \
} while (0)

#define MLP_STEP(IT) do { \
    const int n_ = n0 + (IT); \
    __builtin_amdgcn_wave_barrier(); \
    float4* drow = (float4*)(inw + k * 68); \
    drow[p * 2] = g0; drow[p * 2 + 1] = g1; \
    if (p == 0) { \
        inw[k * 68 + 64] = axv.x - qx; inw[k * 68 + 65] = axv.y - qy; \
        inw[k * 68 + 66] = axv.z - qz; inw[k * 68 + 67] = 0.f; \
    } \
    if (p == 1) flbuf[wave][k] = flv; \
    __builtin_amdgcn_wave_barrier(); \
    if ((IT) < 7) { \
        const int idn_ = idnext; \
        const float4* fr_ = (const float4*)(feat1T + (size_t)(base + idn_) * CF); \
        g0 = fr_[p * 2]; g1 = fr_[p * 2 + 1]; \
        axv = aux4[base + idn_]; flv = flow4[base + idn_]; \
        qx = xyz2[(b * 3 + 0) * N2 + n_ + 1]; \
        qy = xyz2[(b * 3 + 1) * N2 + n_ + 1]; \
        qz = xyz2[(b * 3 + 2) * N2 + n_ + 1]; \
        if ((IT) < 6) idnext = knn_idx[(size_t)(q0 + (IT) + 2) * KNN + k]; \
    } \
    float s00, s01, s02, s03, s04, s05, s06, s07; \
    float s10, s11, s12, s13, s14, s15, s16, s17; \
    float s20, s21, s22, s23, s24, s25, s26, s27; \
    L1L2_QUAD(0, s00,s01,s02,s03, s10,s11,s12,s13, s20,s21,s22,s23); \
    L1L2_QUAD(4, s04,s05,s06,s07, s14,s15,s16,s17, s24,s25,s26,s27); \
    float res0, res1, res2; \
    SMAX8(s00, s01, s02, s03, s04, s05, s06, s07, 0, res0); \
    SMAX8(s10, s11, s12, s13, s14, s15, s16, s17, 1, res1); \
    SMAX8(s20, s21, s22, s23, s24, s25, s26, s27, 2, res2); \
    const float resv = lane == 0 ? res0 : (lane == 1 ? res1 : res2); \
    if (lane < 3) out[((size_t)(b * 3 + lane)) * N2 + n_] = resv; \
} while (0)

__global__ __launch_bounds__(256, 2) void k_mlp5(
    const float* __restrict__ feat1T, const float4* __restrict__ aux4,
    const float4* __restrict__ flow4, const int* __restrict__ knn_idx,
    const float* __restrict__ xyz2,
    const float* __restrict__ W1, const float* __restrict__ b1,
    const float* __restrict__ W2, const float* __restrict__ b2,
    float* __restrict__ out)
{
    __shared__ __align__(16) float w1s[64 * 68];
    __shared__ __align__(16) float inbuf[4][8][68];
    __shared__ __align__(16) float4 flbuf[4][8];

    const int tid  = threadIdx.x;
    const int wave = tid >> 6, lane = tid & 63;

    for (int t = tid; t < 64 * 67; t += 256) {
        const int o = t / 67, c = t - o * 67;
        w1s[o * 68 + c] = W1[t];
    }
    if (tid < 64) w1s[tid * 68 + 67] = 0.f;

    const float b1v = b1[lane];
    const float w2a = W2[lane], w2b = W2[64 + lane], w2c = W2[128 + lane];
    const float b20 = b2[0], b21 = b2[1], b22 = b2[2];
    __syncthreads();

    const float4* wr = (const float4*)&w1s[lane * 68];
    const float4 w0 = wr[0],  w1 = wr[1],  w2 = wr[2],  w3 = wr[3];
    const float4 w4 = wr[4],  w5 = wr[5],  w6 = wr[6],  w7 = wr[7];
    const float4 w8 = wr[8],  w9 = wr[9],  w10 = wr[10], w11 = wr[11];
    const float4 w12 = wr[12], w13 = wr[13], w14 = wr[14], w15 = wr[15];
    const float4 w16 = wr[16];

    const int k = lane >> 3, p = lane & 7;
    float* inw = &inbuf[wave][0][0];
    const float* flf = (const float*)&flbuf[wave][0];

    const int q0   = blockIdx.x * 32 + wave * 8;
    const int b    = q0 >> 14;
    const int base = b * N1;
    const int n0   = q0 & (N2 - 1);

    const int id0v = knn_idx[(size_t)q0 * KNN + k];
    int idnext     = knn_idx[(size_t)(q0 + 1) * KNN + k];

    const float4* fr0 = (const float4*)(feat1T + (size_t)(base + id0v) * CF);
    float4 g0 = fr0[p * 2], g1 = fr0[p * 2 + 1];
    float4 axv = aux4[base + id0v];
    float4 flv = flow4[base + id0v];
    float qx = xyz2[(b * 3 + 0) * N2 + n0];
    float qy = xyz2[(b * 3 + 1) * N2 + n0];
    float qz = xyz2[(b * 3 + 2) * N2 + n0];

    MLP_STEP(0);
    MLP_STEP(1);
    MLP_STEP(2);
    MLP_STEP(3);
    MLP_STEP(4);
    MLP_STEP(5);
    MLP_STEP(6);
    MLP_STEP(7);
}

// ---------------------------------------------------------------------------
extern "C" void kernel_launch(void* const* d_in, const int* in_sizes, int n_in,
                              void* d_out, int out_size, void* d_ws, size_t ws_size,
                              hipStream_t stream)
{
    const float* xyz1  = (const float*)d_in[0];
    const float* xyz2  = (const float*)d_in[1];
    const float* feat1 = (const float*)d_in[2];
    const float* flow  = (const float*)d_in[3];
    const float* W1    = (const float*)d_in[4];
    const float* b1    = (const float*)d_in[5];
    const float* W2    = (const float*)d_in[6];
    const float* b2    = (const float*)d_in[7];
    float* out = (float*)d_out;

    // ws layout: feat1T 2M @0 | aux4 .5M @2M | flow4 .5M @2.5M |
    //            knn_idx 1M @3M | partd 16M @4M | thr .5M @20M |
    //            tneed .5M @20.5M | smask .5M @21M | q4 .5M @21.5M
    char* ws = (char*)d_ws;
    float*  feat1T  = (float*)(ws);
    float4* aux4    = (float4*)(ws + (size_t)(2u << 20));
    float4* flow4   = (float4*)(ws + (size_t)(2u << 20) + (512u << 10));
    int*    knn_idx = (int*)  (ws + (size_t)(3u << 20));
    float*  partd   = (float*)(ws + (size_t)(4u << 20));
    float*  thr     = (float*)(ws + (size_t)(20u << 20));
    int*    tneed   = (int*)  (ws + (size_t)(20u << 20) + (512u << 10));
    int*    smask   = (int*)  (ws + (size_t)(21u << 20));
    float4* q4      = (float4*)(ws + (size_t)(21u << 20) + (512u << 10));

    hipLaunchKernelGGL(k_pack, dim3(N1 / 64, NB), dim3(256), 0, stream,
                       xyz1, xyz2, feat1, flow, feat1T, aux4, flow4, q4);
    hipLaunchKernelGGL(k_knn5, dim3(NQ / 512, SPLIT1), dim3(256), 0, stream,
                       aux4, q4, partd);
    hipLaunchKernelGGL(k_thr, dim3(NQ / 256), dim3(256), 0, stream,
                       partd, thr, tneed, smask);
    hipLaunchKernelGGL(k_sel5, dim3(NQ / 4), dim3(256), 0, stream,
                       aux4, q4, thr, tneed, smask, knn_idx);
    hipLaunchKernelGGL(k_mlp5, dim3(NQ / 32), dim3(256), 0, stream,
                       feat1T, aux4, flow4, knn_idx, xyz2, W1, b1, W2, b2, out);
}